// Round 18
// baseline (320.273 us; speedup 1.0000x reference)
//
#include <hip/hip_runtime.h>

// Stream_PreNet as ONE composed 7x7 conv (exact algebra, proven R11/R17),
// 16x16x32 MFMA. R18 = R17's B-read sharing (1 read -> 2 MFMAs) RESIZED to
// the compiler's proven-safe register zone:
//   block = 8 rows x 16 px x 96 ch (R11's tile); 6 waves = 3 ch-grp x 2 row-grp
//   wave = 32 ch x 16 px x 4 rows -> acc0[4]+acc1[4] = 32 regs (R11-size),
//   wf peak 2x4 frags = 32 regs, live ~84 << 102 cap (launch_bounds(384,5)).
// Block B-reads: 312 vs R11's 624 (6-way wave redundancy -> 3-way).
// R17's failure was acc 64 + wf 40 ~ 125 live -> allocator spill (FETCH+55MB,
// WRITE+160MB, VGPR=84 chosen). Safe zone: acc<=32, phase-local wf<=32.
// Plain stores (NT = 2x write amplification, R13). Pair 49..51 zero-weight:
// g==0 clamps to pair 48 (valid), g>0 zero-B (no OOB/NaN, R3).
// d_ws: wct (96*416 bf16 = 79,872B) + bias2e (96 f32) = 80,256 B.

#define B_   8
#define H_   512
#define W_   256
#define CIN  8
#define COUT 96
#define TH   8            // output rows per block
#define TW   16           // output cols per block
#define RS   (TH + 6)     // 14 staged x rows
#define XC   22           // staged x cols used (TW+6)
#define XCP  23           // padded col stride (16B-aligned chunks, bank rotation)
#define KP   416          // padded K (13 slices of 32)
#define NTHREADS 384      // 6 waves

typedef __bf16 bf16x8 __attribute__((ext_vector_type(8)));
typedef float  f32x4  __attribute__((ext_vector_type(4)));
typedef int    i32x4  __attribute__((ext_vector_type(4)));

__device__ __forceinline__ unsigned short f2bf(float f) {
  unsigned u = __builtin_bit_cast(unsigned, f);
  u += 0x7FFFu + ((u >> 16) & 1u);   // RNE
  return (unsigned short)(u >> 16);
}

__device__ __forceinline__ bf16x8 ld16s(const unsigned short* p) {
  i32x4 t = *(const i32x4*)p;        // 16B load -> ds_read_b128 / dwordx4
  return __builtin_bit_cast(bf16x8, t);
}

__device__ __forceinline__ f32x4 mfma16(bf16x8 a, bf16x8 b, f32x4 c) {
  return __builtin_amdgcn_mfma_f32_16x16x32_bf16(a, b, c, 0, 0, 0);
}

// jnp.pad mode='symmetric': -1->0, -2->1 ; N->N-1, N+1->N-2
__device__ __forceinline__ int symH(int i) { return i < 0 ? -1 - i : (i >= H_ ? 2 * H_ - 1 - i : i); }
__device__ __forceinline__ int symW(int i) { return i < 0 ? -1 - i : (i >= W_ ? 2 * W_ - 1 - i : i); }

// ---- prep: compose Wc = W2(7x1) o W1(1x7) in fp32, cast once to bf16 ----
// wct[n][k], k = p*8 + c, p = th*7+tw (p>=49 zero).  bias2e = b2 + fold(b1).
__global__ void prep_kernel(const float* __restrict__ W1, const float* __restrict__ b1,
                            const float* __restrict__ W2, const float* __restrict__ b2,
                            unsigned short* __restrict__ wct, float* __restrict__ bias2e) {
  int i = blockIdx.x * 256 + threadIdx.x;      // 156 blocks x 256 = 96*416 exactly
  if (i < 96 * KP) {
    int n = i / KP, k = i - n * KP;
    int p = k >> 3, c = k & 7;
    float s = 0.f;
    if (p < 49) {
      int th = p / 7, tw = p - 7 * th;
#pragma unroll 8
      for (int m = 0; m < 96; ++m)             // W2[(th*96+m)*96+n] * W1[(tw*8+c)*96+m]
        s += W2[(th * 96 + m) * 96 + n] * W1[(tw * 8 + c) * 96 + m];
    }
    wct[i] = f2bf(s);
  }
  if (i < 96) {
    float s = b2[i];
#pragma unroll 8
    for (int kc = 0; kc < 672; ++kc) {
      int m = kc - (kc / 96) * 96;
      s += W2[kc * 96 + i] * b1[m];
    }
    bias2e[i] = s;
  }
}

__global__ __launch_bounds__(NTHREADS, 5)      // cap ~102; 3 blocks/CU (R11 setting)
void conv7(const float* __restrict__ x, const unsigned short* __restrict__ wct,
           const float* __restrict__ bias2e, float* __restrict__ out) {
  __shared__ __align__(16) unsigned short xt[RS][XCP][CIN];   // 5,152 B

  const int tid = threadIdx.x;
  const int w0  = blockIdx.x * TW;
  const int h0  = blockIdx.y * TH;
  const int b   = blockIdx.z;

  const int wid  = tid >> 6;        // wave id
  const int lane = tid & 63;
  const int l15  = lane & 15;       // A: ch-in-tile / B,D: pixel
  const int g    = lane >> 4;       // k-group
  const int chg  = wid >> 1;        // ch group 0..2 (32 ch)
  const int rg   = wid & 1;         // row group 0..1 (4 rows)
  const int m0   = rg * 4;          // first output row of this wave
  const int ch0  = chg * 32 + l15;  // A row, tile 0 (tile 1 = +16)

  // ---- stage x halo tile (symmetric pad applied), fp32 -> bf16 ----
  const float* xb = x + (size_t)b * H_ * W_ * CIN;
  if (tid < RS * XC) {
    int rr = tid / XC, cc = tid - rr * XC;
    int hr = symH(h0 - 3 + rr);
    int wc = symW(w0 - 3 + cc);
    const float4* px = (const float4*)(xb + ((size_t)hr * W_ + wc) * CIN);
    float4 v0 = px[0], v1 = px[1];
    unsigned p0 = ((unsigned)f2bf(v0.y) << 16) | f2bf(v0.x);
    unsigned p1 = ((unsigned)f2bf(v0.w) << 16) | f2bf(v0.z);
    unsigned p2 = ((unsigned)f2bf(v1.y) << 16) | f2bf(v1.x);
    unsigned p3 = ((unsigned)f2bf(v1.w) << 16) | f2bf(v1.z);
    *(i32x4*)&xt[rr][cc][0] = (i32x4){(int)p0, (int)p1, (int)p2, (int)p3};
  }

  const unsigned short* wrow0 = wct + (size_t)ch0 * KP;
  const unsigned short* wrow1 = wrow0 + (size_t)16 * KP;
  const unsigned short* xtf   = &xt[0][0][0];
  const i32x4 z4 = {0, 0, 0, 0};

  f32x4 acc0[4], acc1[4];
#pragma unroll
  for (int m = 0; m < 4; ++m) { acc0[m] = (f32x4){0,0,0,0}; acc1[m] = (f32x4){0,0,0,0}; }

  __syncthreads();

#define ROWSTR (XCP * CIN)           // 184 elements per staged row

  // one pass: NS slices from S0; wf loaded at top, consumed immediately
  // (the ONLY register shape this compiler handles without spilling).
  // slice s, k-group g -> pair p=4s+g; th=p/7 (magic), tw=p%7.
  // B[k][n=pix l15] = xt[m0+m+th][l15+tw][c]; ONE read feeds acc0 AND acc1.
#define PASS(S0, NS, HAS_TAIL)                                                  \
  { bf16x8 wf0[NS], wf1[NS];                                                    \
    _Pragma("unroll") for (int s2 = 0; s2 < (NS); ++s2) {                       \
      wf0[s2] = ld16s(&wrow0[32 * ((S0) + s2) + 8 * g]);                        \
      wf1[s2] = ld16s(&wrow1[32 * ((S0) + s2) + 8 * g]);                        \
    }                                                                           \
    _Pragma("unroll") for (int s2 = 0; s2 < (NS); ++s2) {                       \
      int p = 4 * ((S0) + s2) + g;                                              \
      int pc = p > 48 ? 48 : p;                                                 \
      int th = (pc * 9363) >> 16;            /* /7 magic, exact for pc<=48 */   \
      int tw = pc - 7 * th;                                                     \
      const unsigned short* bp = xtf + (m0 + th) * ROWSTR + (l15 + tw) * CIN;   \
      const bool tail = (HAS_TAIL) && ((S0) + s2 == 12) && (g != 0);            \
      _Pragma("unroll") for (int m = 0; m < 4; ++m) {                           \
        bf16x8 xv = tail ? __builtin_bit_cast(bf16x8, z4)                       \
                         : ld16s(bp + m * ROWSTR);                              \
        acc0[m] = mfma16(wf0[s2], xv, acc0[m]);                                 \
        acc1[m] = mfma16(wf1[s2], xv, acc1[m]);                                 \
      }                                                                         \
    } }

#pragma unroll 1
  for (int pass = 0; pass < 4; ++pass) {
    if (pass == 0)      { PASS(0, 4, 0) }
    else if (pass == 1) { PASS(4, 3, 0) }
    else if (pass == 2) { PASS(7, 3, 0) }
    else                { PASS(10, 3, 1) }
  }
#undef PASS

  // ---- epilogue: lane = pixel l15, channels chg*32 + {4g..4g+3, 16+4g..} ----
  const float4 bia0 = *(const float4*)&bias2e[chg * 32 + 4 * g];
  const float4 bia1 = *(const float4*)&bias2e[chg * 32 + 16 + 4 * g];
  const size_t ob0 = (((size_t)b * H_ + h0 + m0) * W_ + (w0 + l15)) * COUT + chg * 32 + 4 * g;
#pragma unroll
  for (int m = 0; m < 4; ++m) {
    f32x4 v0 = acc0[m], v1 = acc1[m];
    v0[0] += bia0.x; v0[1] += bia0.y; v0[2] += bia0.z; v0[3] += bia0.w;
    v1[0] += bia1.x; v1[1] += bia1.y; v1[2] += bia1.z; v1[3] += bia1.w;
    const size_t ob = ob0 + (size_t)m * (W_ * COUT);
    *(f32x4*)(out + ob)      = v0;
    *(f32x4*)(out + ob + 16) = v1;
  }
}

extern "C" void kernel_launch(void* const* d_in, const int* in_sizes, int n_in,
                              void* d_out, int out_size, void* d_ws, size_t ws_size,
                              hipStream_t stream) {
  const float* x  = (const float*)d_in[0];
  const float* W1 = (const float*)d_in[1];
  const float* b1 = (const float*)d_in[2];
  const float* W2 = (const float*)d_in[3];
  const float* b2 = (const float*)d_in[4];
  // d_in[5] = training (unused)

  unsigned short* wct = (unsigned short*)d_ws;       // 96*416 u16
  float* bias2e = (float*)(wct + 96 * KP);           // 96 f32
  float* out = (float*)d_out;

  prep_kernel<<<dim3(156), dim3(256), 0, stream>>>(W1, b1, W2, b2, wct, bias2e);
  conv7<<<dim3(W_ / TW, H_ / TH, B_), dim3(NTHREADS), 0, stream>>>(
      x, wct, bias2e, out);
}